// Round 5
// baseline (9837.440 us; speedup 1.0000x reference)
//
#include <hip/hip_runtime.h>
#include <cmath>

// Problem constants: B=16, T=512, S=320, H=512, K=1024, NQ=4, M=B*T=8192

// ---------------- generic 64x64 tile f32 GEMM ----------------
template<bool BT>
__global__ __launch_bounds__(256)
void gemm64(const float* __restrict__ A, const float* __restrict__ B,
            float* __restrict__ C, int M, int N, int K,
            const float* __restrict__ bias1, const float* __restrict__ bias2)
{
    __shared__ float Al[32][68];
    __shared__ float Bl[32][68];
    const int m0 = blockIdx.y * 64, n0 = blockIdx.x * 64;
    const int t = threadIdx.x;
    const int tm = t >> 4, tn = t & 15;
    float acc[4][4] = {{0.f, 0.f, 0.f, 0.f}};

    for (int k0 = 0; k0 < K; k0 += 32) {
        #pragma unroll
        for (int i = 0; i < 2; i++) {
            int f4 = t + i * 256;
            int row = f4 >> 3, c4 = f4 & 7;
            float4 v = *(const float4*)(A + (size_t)(m0 + row) * K + k0 + c4 * 4);
            Al[c4*4+0][row] = v.x; Al[c4*4+1][row] = v.y;
            Al[c4*4+2][row] = v.z; Al[c4*4+3][row] = v.w;
        }
        if (BT) {
            #pragma unroll
            for (int i = 0; i < 2; i++) {
                int f4 = t + i * 256;
                int row = f4 >> 3, c4 = f4 & 7;
                float4 v = *(const float4*)(B + (size_t)(n0 + row) * K + k0 + c4 * 4);
                Bl[c4*4+0][row] = v.x; Bl[c4*4+1][row] = v.y;
                Bl[c4*4+2][row] = v.z; Bl[c4*4+3][row] = v.w;
            }
        } else {
            #pragma unroll
            for (int i = 0; i < 2; i++) {
                int f4 = t + i * 256;
                int kk = f4 >> 4, c4 = f4 & 15;
                float4 v = *(const float4*)(B + (size_t)(k0 + kk) * N + n0 + c4 * 4);
                *(float4*)&Bl[kk][c4 * 4] = v;
            }
        }
        __syncthreads();
        #pragma unroll
        for (int k = 0; k < 32; k++) {
            float4 a4 = *(const float4*)&Al[k][tm * 4];
            float4 b4 = *(const float4*)&Bl[k][tn * 4];
            float av[4] = {a4.x, a4.y, a4.z, a4.w};
            float bv[4] = {b4.x, b4.y, b4.z, b4.w};
            #pragma unroll
            for (int i = 0; i < 4; i++)
                #pragma unroll
                for (int j = 0; j < 4; j++)
                    acc[i][j] = fmaf(av[i], bv[j], acc[i][j]);
        }
        __syncthreads();
    }
    float bn[4];
    #pragma unroll
    for (int j = 0; j < 4; j++) {
        float bb = 0.f;
        if (bias1) bb += bias1[n0 + tn * 4 + j];
        if (bias2) bb += bias2[n0 + tn * 4 + j];
        bn[j] = bb;
    }
    #pragma unroll
    for (int i = 0; i < 4; i++) {
        float4 o;
        o.x = acc[i][0] + bn[0]; o.y = acc[i][1] + bn[1];
        o.z = acc[i][2] + bn[2]; o.w = acc[i][3] + bn[3];
        *(float4*)(C + (size_t)(m0 + tm * 4 + i) * N + n0 + tn * 4) = o;
    }
}

// ---------------- LayerNorm + ReLU in place ----------------
__global__ __launch_bounds__(256)
void ln_relu_kernel(float* __restrict__ X, const float* __restrict__ g,
                    const float* __restrict__ bb)
{
    __shared__ float red[256];
    __shared__ float stat[2];
    const int row = blockIdx.x, t = threadIdx.x;
    float x0 = X[(size_t)row * 512 + t];
    float x1 = X[(size_t)row * 512 + 256 + t];
    red[t] = x0 + x1;
    __syncthreads();
    for (int o = 128; o > 0; o >>= 1) { if (t < o) red[t] += red[t + o]; __syncthreads(); }
    if (t == 0) stat[0] = red[0] * (1.f / 512.f);
    __syncthreads();
    float mu = stat[0];
    float d0 = x0 - mu, d1 = x1 - mu;
    red[t] = d0 * d0 + d1 * d1;
    __syncthreads();
    for (int o = 128; o > 0; o >>= 1) { if (t < o) red[t] += red[t + o]; __syncthreads(); }
    if (t == 0) stat[1] = red[0] * (1.f / 512.f);
    __syncthreads();
    float rs = rsqrtf(stat[1] + 1e-5f);
    float y0 = d0 * rs * g[t] + bb[t];
    float y1 = d1 * rs * g[256 + t] + bb[256 + t];
    X[(size_t)row * 512 + t] = fmaxf(y0, 0.f);
    X[(size_t)row * 512 + 256 + t] = fmaxf(y1, 0.f);
}

// ---------------- codebook row squared-norms ----------------
__global__ __launch_bounds__(256)
void rownorm_kernel(const float* __restrict__ Ein, float* __restrict__ norms)
{
    __shared__ float red[256];
    const int row = blockIdx.x, t = threadIdx.x;
    float a = Ein[(size_t)row * 512 + t];
    float b = Ein[(size_t)row * 512 + 256 + t];
    red[t] = a * a + b * b;
    __syncthreads();
    for (int o = 128; o > 0; o >>= 1) { if (t < o) red[t] += red[t + o]; __syncthreads(); }
    if (t == 0) norms[row] = red[0];
}

// ---------------- VQ argmin + STE update ----------------
__global__ __launch_bounds__(256)
void vq_update_kernel(const float* __restrict__ D, const float* __restrict__ norms,
                      const float* __restrict__ cb, float* __restrict__ residual,
                      float* __restrict__ quant, float* __restrict__ loss_acc,
                      int first)
{
    __shared__ unsigned long long red[256];
    __shared__ float fred[256];
    __shared__ int sidx;
    __shared__ float sdmin;
    const int tok = blockIdx.x, t = threadIdx.x;
    unsigned long long best = ~0ull;
    #pragma unroll
    for (int i = 0; i < 4; i++) {
        int k = t + i * 256;
        float d = fmaf(-2.f, D[(size_t)tok * 1024 + k], norms[k]);
        unsigned u = __float_as_uint(d);
        u = (u & 0x80000000u) ? ~u : (u | 0x80000000u);
        unsigned long long p = ((unsigned long long)u << 32) | (unsigned)k;
        best = p < best ? p : best;
    }
    red[t] = best;
    __syncthreads();
    for (int o = 128; o > 0; o >>= 1) {
        if (t < o) red[t] = red[t + o] < red[t] ? red[t + o] : red[t];
        __syncthreads();
    }
    if (t == 0) {
        unsigned long long r0 = red[0];
        sidx = (int)(r0 & 0xffffffffu);
        unsigned uv = (unsigned)(r0 >> 32);
        unsigned orig = (uv & 0x80000000u) ? (uv ^ 0x80000000u) : ~uv;
        sdmin = __uint_as_float(orig);
    }
    float r0v = residual[(size_t)tok * 512 + t];
    float r1v = residual[(size_t)tok * 512 + 256 + t];
    fred[t] = r0v * r0v + r1v * r1v;
    __syncthreads();
    for (int o = 128; o > 0; o >>= 1) { if (t < o) fred[t] += fred[t + o]; __syncthreads(); }
    int idx = sidx;
    if (t == 0) atomicAdd(loss_acc, sdmin + fred[0]);
    const float* E = cb + (size_t)idx * 512;
    float e0 = E[t], e1 = E[256 + t];
    float q0 = r0v + (e0 - r0v);
    float q1 = r1v + (e1 - r1v);
    residual[(size_t)tok * 512 + t]       = r0v - q0;
    residual[(size_t)tok * 512 + 256 + t] = r1v - q1;
    if (first) {
        quant[(size_t)tok * 512 + t]       = q0;
        quant[(size_t)tok * 512 + 256 + t] = q1;
    } else {
        quant[(size_t)tok * 512 + t]       += q0;
        quant[(size_t)tok * 512 + 256 + t] += q1;
    }
}

// ---------------- fused 2-layer LSTM: merged roles, 1 drain/step ----------------
#define GRPSZ 32
#define NGRP 8

__device__ __forceinline__ void wait_vm0() {
    asm volatile("s_waitcnt vmcnt(0)" ::: "memory");
}

// 4 coherent 16B loads, NO wait (caller drains once for all in-flight loads)
__device__ __forceinline__ void ld4_nw(float4& a, float4& b, float4& c, float4& d,
                                       const float4* p0, const float4* p1,
                                       const float4* p2, const float4* p3)
{
    asm volatile(
        "global_load_dwordx4 %0, %4, off sc0 sc1\n\t"
        "global_load_dwordx4 %1, %5, off sc0 sc1\n\t"
        "global_load_dwordx4 %2, %6, off sc0 sc1\n\t"
        "global_load_dwordx4 %3, %7, off sc0 sc1"
        : "=&v"(a), "=&v"(b), "=&v"(c), "=&v"(d)
        : "v"(p0), "v"(p1), "v"(p2), "v"(p3)
        : "memory");
}

__device__ __forceinline__ void arrive_wait(unsigned* bar, int g, unsigned tgt)
{
    unsigned r = __hip_atomic_fetch_add(bar + g * 32, 1u, __ATOMIC_RELAXED,
                                        __HIP_MEMORY_SCOPE_AGENT);
    if (r == tgt * GRPSZ - 1) {
        unsigned rr = __hip_atomic_fetch_add(bar + 256, 1u, __ATOMIC_RELAXED,
                                             __HIP_MEMORY_SCOPE_AGENT);
        if (rr == tgt * NGRP - 1)
            __hip_atomic_store(bar + 288, tgt, __ATOMIC_RELAXED,
                               __HIP_MEMORY_SCOPE_AGENT);
    }
    int spins = 0;
    while (__hip_atomic_load(bar + 288, __ATOMIC_RELAXED,
                             __HIP_MEMORY_SCOPE_AGENT) < tgt) {
        __builtin_amdgcn_s_sleep(2);
        if (++spins > 30000) break;
    }
}

__device__ __forceinline__ float dot32(const float* hb, const float (&w)[32])
{
    float a0 = 0.f, a1 = 0.f, a2 = 0.f, a3 = 0.f;
    #pragma unroll
    for (int k4 = 0; k4 < 8; k4++) {
        float4 h4 = ((const float4*)hb)[k4];
        a0 = fmaf(h4.x, w[k4 * 4 + 0], a0);
        a1 = fmaf(h4.y, w[k4 * 4 + 1], a1);
        a2 = fmaf(h4.z, w[k4 * 4 + 2], a2);
        a3 = fmaf(h4.w, w[k4 * 4 + 3], a3);
    }
    return (a0 + a1) + (a2 + a3);
}

// 256 blocks; block owns h1 units {2bid,2bid+1} AND h2 units {2bid,2bid+1}.
// Iteration s: compute h1[s] (s<512) and h2[s-1] (s>=1). Both inputs
// (h1[s-1], h2[s-2]) are published at barrier generation s+1.
// h{1,2}[k] lives in buffer k&1 (0=A, 1=B); h1[-1],h2[-1] = zeroed B buffers.
__global__ __launch_bounds__(256)
void lstm_fused_kernel(const float* __restrict__ P1,
                       const float* __restrict__ wh1,
                       const float* __restrict__ wi2,
                       const float* __restrict__ wh2,
                       const float* __restrict__ bi2,
                       const float* __restrict__ bh2,
                       float* __restrict__ H2out,
                       float* __restrict__ h1A, float* __restrict__ h1B,
                       float* __restrict__ h2A, float* __restrict__ h2B,
                       unsigned* __restrict__ bar)
{
    __shared__ float hl1[16 * 512];        // 32 KB: h1[s-1] (L1 h-dot AND L2 x-dot)
    __shared__ float hl2[16 * 512];        // 32 KB: h2[s-2]
    __shared__ float part[16 * 257];       // padded stride 257: bank-spread
    __shared__ float gl[256];              // 16 cols x 16 batch
    __shared__ float c_l1[32], c_l2[32];   // cell states (2 units x 16 batch)

    const int t = threadIdx.x, bid = blockIdx.x;
    const int g = bid >> 5;
    // dot-phase mapping: cl = gate-column (wave-uniform by quarter), ks = K-slice
    const int cl = t >> 4, ks = t & 15;
    const int cc = cl & 7, gate_d = cc >> 1, jj_d = cc & 1;
    // reduce-phase mapping
    const int rc = t >> 4, rb = t & 15;
    const int rcc = rc & 7, gate_r = rcc >> 1, jj_r = rcc & 1;
    const int j2 = 2 * bid;

    float w1[32];   // L1 threads: wh1 row  |  L2 threads: wi2 row
    float w2[32];   // L2 threads: wh2 row
    {
        const float* wrow = ((cl < 8) ? wh1 : wi2)
                          + (size_t)(gate_d * 512 + j2 + jj_d) * 512 + ks * 32;
        #pragma unroll
        for (int i = 0; i < 32; i++) w1[i] = wrow[i];
    }
    if (cl >= 8) {
        const float* wrow = wh2 + (size_t)(gate_d * 512 + j2 + jj_d) * 512 + ks * 32;
        #pragma unroll
        for (int i = 0; i < 32; i++) w2[i] = wrow[i];
    } else {
        #pragma unroll
        for (int i = 0; i < 32; i++) w2[i] = 0.f;
    }
    float bias2v = 0.f;
    if (rc >= 8) {
        int col = gate_r * 512 + j2 + jj_r;
        bias2v = bi2[col] + bh2[col];
    }
    // init: zero cell state; zero h1[-1], h2[-1] (the B buffers)
    if (t < 32) {
        c_l1[t] = 0.f; c_l2[t] = 0.f;
        int b = t >> 1, jj = t & 1;
        __hip_atomic_store(&h1B[b * 512 + j2 + jj], 0.f,
                           __ATOMIC_RELAXED, __HIP_MEMORY_SCOPE_AGENT);
        __hip_atomic_store(&h2B[b * 512 + j2 + jj], 0.f,
                           __ATOMIC_RELAXED, __HIP_MEMORY_SCOPE_AGENT);
    }
    wait_vm0();
    __syncthreads();
    if (t == 0) arrive_wait(bar, g, 1);
    __syncthreads();

    for (int s = 0; s <= 512; s++) {
        // ---- stage h1[s-1] and h2[s-2]: 16 loads, ONE drain ----
        {
            const float* h1src = (s & 1) ? h1A : h1B;   // buffer (s-1)&1
            const float* h2src = (s & 1) ? h2B : h2A;   // buffer s&1 -> h2[s-2]
            const float4* a4 = (const float4*)h1src;
            const float4* b4 = (const float4*)h2src;
            float4 r0,r1,r2,r3,r4,r5,r6,r7,r8,r9,r10,r11,r12,r13,r14,r15;
            ld4_nw(r0, r1, r2, r3,   a4 + t,        a4 + t + 256,  a4 + t + 512,  a4 + t + 768);
            ld4_nw(r4, r5, r6, r7,   a4 + t + 1024, a4 + t + 1280, a4 + t + 1536, a4 + t + 1792);
            ld4_nw(r8, r9, r10,r11,  b4 + t,        b4 + t + 256,  b4 + t + 512,  b4 + t + 768);
            ld4_nw(r12,r13,r14,r15,  b4 + t + 1024, b4 + t + 1280, b4 + t + 1536, b4 + t + 1792);
            wait_vm0();
            float4* d1 = (float4*)hl1; float4* d2 = (float4*)hl2;
            d1[t] = r0;        d1[t + 256] = r1;  d1[t + 512] = r2;  d1[t + 768] = r3;
            d1[t + 1024] = r4; d1[t + 1280] = r5; d1[t + 1536] = r6; d1[t + 1792] = r7;
            d2[t] = r8;        d2[t + 256] = r9;  d2[t + 512] = r10; d2[t + 768] = r11;
            d2[t + 1024] = r12; d2[t + 1280] = r13; d2[t + 1536] = r14; d2[t + 1792] = r15;
        }
        // prefetch P1 gate value (cached load, in flight during dot phase)
        float pv = 0.f;
        if (rc < 8 && s < 512)
            pv = P1[(size_t)(rb * 512 + s) * 2048 + gate_r * 512 + j2 + jj_r];
        __syncthreads();

        // ---- dot phase (wave-uniform split: waves 0-1 L1, waves 2-3 L2) ----
        float accb[16];
        if (cl < 8) {
            if (s < 512) {
                #pragma unroll
                for (int b = 0; b < 16; b++)
                    accb[b] = dot32(hl1 + b * 512 + ks * 32, w1);
            } else {
                #pragma unroll
                for (int b = 0; b < 16; b++) accb[b] = 0.f;
            }
        } else {
            if (s >= 1) {
                #pragma unroll
                for (int b = 0; b < 16; b++)
                    accb[b] = dot32(hl1 + b * 512 + ks * 32, w1)
                            + dot32(hl2 + b * 512 + ks * 32, w2);
            } else {
                #pragma unroll
                for (int b = 0; b < 16; b++) accb[b] = 0.f;
            }
        }
        #pragma unroll
        for (int b = 0; b < 16; b++)
            part[ks * 257 + cl * 16 + b] = accb[b];
        __syncthreads();

        // ---- reduce + bias ----
        {
            float gv = (rc < 8) ? pv : bias2v;
            #pragma unroll
            for (int k = 0; k < 16; k++)
                gv += part[k * 257 + rc * 16 + rb];
            gl[rc * 16 + rb] = gv;
        }
        __syncthreads();

        // ---- cell update + coherent h store ----
        if (t < 64) {
            if (t < 32) {
                if (s < 512) {
                    int jj = t >> 4, b = t & 15;
                    float iv = gl[(0 + jj) * 16 + b];
                    float fv = gl[(2 + jj) * 16 + b];
                    float gg = gl[(4 + jj) * 16 + b];
                    float ov = gl[(6 + jj) * 16 + b];
                    float ig = 1.f / (1.f + expf(-iv));
                    float fg = 1.f / (1.f + expf(-fv));
                    float og = 1.f / (1.f + expf(-ov));
                    float cn = fg * c_l1[jj * 16 + b] + ig * tanhf(gg);
                    float hn = og * tanhf(cn);
                    c_l1[jj * 16 + b] = cn;
                    float* hout = (s & 1) ? h1B : h1A;       // buffer s&1
                    __hip_atomic_store(&hout[b * 512 + j2 + jj], hn,
                                       __ATOMIC_RELAXED, __HIP_MEMORY_SCOPE_AGENT);
                }
            } else {
                if (s >= 1) {
                    int tt = t - 32;
                    int jj = tt >> 4, b = tt & 15;
                    int m = s - 1;
                    float iv = gl[(8 + 0 + jj) * 16 + b];
                    float fv = gl[(8 + 2 + jj) * 16 + b];
                    float gg = gl[(8 + 4 + jj) * 16 + b];
                    float ov = gl[(8 + 6 + jj) * 16 + b];
                    float ig = 1.f / (1.f + expf(-iv));
                    float fg = 1.f / (1.f + expf(-fv));
                    float og = 1.f / (1.f + expf(-ov));
                    float cn = fg * c_l2[jj * 16 + b] + ig * tanhf(gg);
                    float hn = og * tanhf(cn);
                    c_l2[jj * 16 + b] = cn;
                    float* hout = (s & 1) ? h2A : h2B;       // buffer (s-1)&1
                    __hip_atomic_store(&hout[b * 512 + j2 + jj], hn,
                                       __ATOMIC_RELAXED, __HIP_MEMORY_SCOPE_AGENT);
                    H2out[(size_t)(b * 512 + m) * 512 + j2 + jj] = hn;
                }
            }
        }
        if (s < 512) {
            wait_vm0();                       // drain write-through h stores
            if (t == 0) arrive_wait(bar, g, (unsigned)(s + 2));
            __syncthreads();
        }
    }
}

__global__ void finalize_loss_kernel(const float* __restrict__ acc, float* __restrict__ out)
{
    int q = threadIdx.x;
    if (q < 4) out[2621440 + q] = acc[q] * (1.f / 4194304.f);
}

extern "C" void kernel_launch(void* const* d_in, const int* in_sizes, int n_in,
                              void* d_out, int out_size, void* d_ws, size_t ws_size,
                              hipStream_t stream)
{
    const float* waveform  = (const float*)d_in[0];
    const float* enc_w     = (const float*)d_in[1];
    const float* enc_b     = (const float*)d_in[2];
    const float* ln_g      = (const float*)d_in[3];
    const float* ln_b      = (const float*)d_in[4];
    const float* codebooks = (const float*)d_in[5];
    const float* lstm_wi   = (const float*)d_in[6];
    const float* lstm_wh   = (const float*)d_in[7];
    const float* lstm_bi   = (const float*)d_in[8];
    const float* lstm_bh   = (const float*)d_in[9];
    const float* dec_w     = (const float*)d_in[10];
    const float* dec_b     = (const float*)d_in[11];
    float* out = (float*)d_out;

    float* ws = (float*)d_ws;                  // float offsets
    float* residual = ws;                      // 4,194,304
    float* quant    = ws + 4194304;            // 4,194,304
    float* H2       = ws + 8388608;            // 4,194,304
    float* big      = ws + 12582912;           // 16,777,216 (VQ D, then LSTM P1)
    float* h1A      = ws + 29360128;           // 8192
    float* h1B      = ws + 29368320;           // 8192
    float* h2A      = ws + 29376512;           // 8192
    float* h2B      = ws + 29384704;           // 8192
    float* norms    = ws + 29392896;           // 4096
    float* loss_acc = ws + 29396992;           // 16
    unsigned* bar   = (unsigned*)(ws + 29397504); // 512 u32

    hipMemsetAsync(loss_acc, 0, 16 * sizeof(float), stream);
    hipMemsetAsync(bar, 0, 512 * sizeof(unsigned), stream);

    // Encoder
    gemm64<false><<<dim3(8, 128), 256, 0, stream>>>(waveform, enc_w, residual,
                                                    8192, 512, 320, enc_b, nullptr);
    ln_relu_kernel<<<8192, 256, 0, stream>>>(residual, ln_g, ln_b);

    // Residual VQ
    rownorm_kernel<<<4096, 256, 0, stream>>>(codebooks, norms);
    for (int q = 0; q < 4; q++) {
        const float* cb = codebooks + (size_t)q * 1024 * 512;
        gemm64<true><<<dim3(16, 128), 256, 0, stream>>>(residual, cb, big,
                                                        8192, 1024, 512, nullptr, nullptr);
        vq_update_kernel<<<8192, 256, 0, stream>>>(big, norms + q * 1024, cb,
                                                   residual, quant, loss_acc + q, q == 0);
    }

    // P1 = quant @ wi1^T + bi1 + bh1
    gemm64<true><<<dim3(32, 128), 256, 0, stream>>>(quant, lstm_wi, big,
                                                    8192, 2048, 512, lstm_bi, lstm_bh);
    // Fused 2-layer LSTM — merged roles, single-drain staging
    lstm_fused_kernel<<<dim3(256), dim3(256), 0, stream>>>(
        big, lstm_wh, lstm_wi + (size_t)2048 * 512, lstm_wh + (size_t)2048 * 512,
        lstm_bi + 2048, lstm_bh + 2048, H2, h1A, h1B, h2A, h2B, bar);

    // Decoder -> d_out
    gemm64<false><<<dim3(5, 128), 256, 0, stream>>>(H2, dec_w, out,
                                                    8192, 320, 512, dec_b, nullptr);
    finalize_loss_kernel<<<1, 4, 0, stream>>>(loss_acc, out);
}

// Round 6
// 6129.922 us; speedup vs baseline: 1.6048x; 1.6048x over previous
//
#include <hip/hip_runtime.h>
#include <cmath>

// Problem constants: B=16, T=512, S=320, H=512, K=1024, NQ=4, M=B*T=8192

// ---------------- generic 64x64 tile f32 GEMM ----------------
template<bool BT>
__global__ __launch_bounds__(256)
void gemm64(const float* __restrict__ A, const float* __restrict__ B,
            float* __restrict__ C, int M, int N, int K,
            const float* __restrict__ bias1, const float* __restrict__ bias2)
{
    __shared__ float Al[32][68];
    __shared__ float Bl[32][68];
    const int m0 = blockIdx.y * 64, n0 = blockIdx.x * 64;
    const int t = threadIdx.x;
    const int tm = t >> 4, tn = t & 15;
    float acc[4][4] = {{0.f, 0.f, 0.f, 0.f}};

    for (int k0 = 0; k0 < K; k0 += 32) {
        #pragma unroll
        for (int i = 0; i < 2; i++) {
            int f4 = t + i * 256;
            int row = f4 >> 3, c4 = f4 & 7;
            float4 v = *(const float4*)(A + (size_t)(m0 + row) * K + k0 + c4 * 4);
            Al[c4*4+0][row] = v.x; Al[c4*4+1][row] = v.y;
            Al[c4*4+2][row] = v.z; Al[c4*4+3][row] = v.w;
        }
        if (BT) {
            #pragma unroll
            for (int i = 0; i < 2; i++) {
                int f4 = t + i * 256;
                int row = f4 >> 3, c4 = f4 & 7;
                float4 v = *(const float4*)(B + (size_t)(n0 + row) * K + k0 + c4 * 4);
                Bl[c4*4+0][row] = v.x; Bl[c4*4+1][row] = v.y;
                Bl[c4*4+2][row] = v.z; Bl[c4*4+3][row] = v.w;
            }
        } else {
            #pragma unroll
            for (int i = 0; i < 2; i++) {
                int f4 = t + i * 256;
                int kk = f4 >> 4, c4 = f4 & 15;
                float4 v = *(const float4*)(B + (size_t)(k0 + kk) * N + n0 + c4 * 4);
                *(float4*)&Bl[kk][c4 * 4] = v;
            }
        }
        __syncthreads();
        #pragma unroll
        for (int k = 0; k < 32; k++) {
            float4 a4 = *(const float4*)&Al[k][tm * 4];
            float4 b4 = *(const float4*)&Bl[k][tn * 4];
            float av[4] = {a4.x, a4.y, a4.z, a4.w};
            float bv[4] = {b4.x, b4.y, b4.z, b4.w};
            #pragma unroll
            for (int i = 0; i < 4; i++)
                #pragma unroll
                for (int j = 0; j < 4; j++)
                    acc[i][j] = fmaf(av[i], bv[j], acc[i][j]);
        }
        __syncthreads();
    }
    float bn[4];
    #pragma unroll
    for (int j = 0; j < 4; j++) {
        float bb = 0.f;
        if (bias1) bb += bias1[n0 + tn * 4 + j];
        if (bias2) bb += bias2[n0 + tn * 4 + j];
        bn[j] = bb;
    }
    #pragma unroll
    for (int i = 0; i < 4; i++) {
        float4 o;
        o.x = acc[i][0] + bn[0]; o.y = acc[i][1] + bn[1];
        o.z = acc[i][2] + bn[2]; o.w = acc[i][3] + bn[3];
        *(float4*)(C + (size_t)(m0 + tm * 4 + i) * N + n0 + tn * 4) = o;
    }
}

// ---------------- LayerNorm + ReLU in place ----------------
__global__ __launch_bounds__(256)
void ln_relu_kernel(float* __restrict__ X, const float* __restrict__ g,
                    const float* __restrict__ bb)
{
    __shared__ float red[256];
    __shared__ float stat[2];
    const int row = blockIdx.x, t = threadIdx.x;
    float x0 = X[(size_t)row * 512 + t];
    float x1 = X[(size_t)row * 512 + 256 + t];
    red[t] = x0 + x1;
    __syncthreads();
    for (int o = 128; o > 0; o >>= 1) { if (t < o) red[t] += red[t + o]; __syncthreads(); }
    if (t == 0) stat[0] = red[0] * (1.f / 512.f);
    __syncthreads();
    float mu = stat[0];
    float d0 = x0 - mu, d1 = x1 - mu;
    red[t] = d0 * d0 + d1 * d1;
    __syncthreads();
    for (int o = 128; o > 0; o >>= 1) { if (t < o) red[t] += red[t + o]; __syncthreads(); }
    if (t == 0) stat[1] = red[0] * (1.f / 512.f);
    __syncthreads();
    float rs = rsqrtf(stat[1] + 1e-5f);
    float y0 = d0 * rs * g[t] + bb[t];
    float y1 = d1 * rs * g[256 + t] + bb[256 + t];
    X[(size_t)row * 512 + t] = fmaxf(y0, 0.f);
    X[(size_t)row * 512 + 256 + t] = fmaxf(y1, 0.f);
}

// ---------------- codebook row squared-norms ----------------
__global__ __launch_bounds__(256)
void rownorm_kernel(const float* __restrict__ Ein, float* __restrict__ norms)
{
    __shared__ float red[256];
    const int row = blockIdx.x, t = threadIdx.x;
    float a = Ein[(size_t)row * 512 + t];
    float b = Ein[(size_t)row * 512 + 256 + t];
    red[t] = a * a + b * b;
    __syncthreads();
    for (int o = 128; o > 0; o >>= 1) { if (t < o) red[t] += red[t + o]; __syncthreads(); }
    if (t == 0) norms[row] = red[0];
}

// ---------------- VQ argmin + STE update ----------------
__global__ __launch_bounds__(256)
void vq_update_kernel(const float* __restrict__ D, const float* __restrict__ norms,
                      const float* __restrict__ cb, float* __restrict__ residual,
                      float* __restrict__ quant, float* __restrict__ loss_acc,
                      int first)
{
    __shared__ unsigned long long red[256];
    __shared__ float fred[256];
    __shared__ int sidx;
    __shared__ float sdmin;
    const int tok = blockIdx.x, t = threadIdx.x;
    unsigned long long best = ~0ull;
    #pragma unroll
    for (int i = 0; i < 4; i++) {
        int k = t + i * 256;
        float d = fmaf(-2.f, D[(size_t)tok * 1024 + k], norms[k]);
        unsigned u = __float_as_uint(d);
        u = (u & 0x80000000u) ? ~u : (u | 0x80000000u);
        unsigned long long p = ((unsigned long long)u << 32) | (unsigned)k;
        best = p < best ? p : best;
    }
    red[t] = best;
    __syncthreads();
    for (int o = 128; o > 0; o >>= 1) {
        if (t < o) red[t] = red[t + o] < red[t] ? red[t + o] : red[t];
        __syncthreads();
    }
    if (t == 0) {
        unsigned long long r0 = red[0];
        sidx = (int)(r0 & 0xffffffffu);
        unsigned uv = (unsigned)(r0 >> 32);
        unsigned orig = (uv & 0x80000000u) ? (uv ^ 0x80000000u) : ~uv;
        sdmin = __uint_as_float(orig);
    }
    float r0v = residual[(size_t)tok * 512 + t];
    float r1v = residual[(size_t)tok * 512 + 256 + t];
    fred[t] = r0v * r0v + r1v * r1v;
    __syncthreads();
    for (int o = 128; o > 0; o >>= 1) { if (t < o) fred[t] += fred[t + o]; __syncthreads(); }
    int idx = sidx;
    if (t == 0) atomicAdd(loss_acc, sdmin + fred[0]);
    const float* E = cb + (size_t)idx * 512;
    float e0 = E[t], e1 = E[256 + t];
    float q0 = r0v + (e0 - r0v);
    float q1 = r1v + (e1 - r1v);
    residual[(size_t)tok * 512 + t]       = r0v - q0;
    residual[(size_t)tok * 512 + 256 + t] = r1v - q1;
    if (first) {
        quant[(size_t)tok * 512 + t]       = q0;
        quant[(size_t)tok * 512 + 256 + t] = q1;
    } else {
        quant[(size_t)tok * 512 + t]       += q0;
        quant[(size_t)tok * 512 + 256 + t] += q1;
    }
}

// ---------------- fused 2-layer LSTM: merged roles, uniform dot, 1 drain ----------------
#define GRPSZ 32
#define NGRP 8

__device__ __forceinline__ void wait_vm0() {
    asm volatile("s_waitcnt vmcnt(0)" ::: "memory");
}

// 4 coherent 16B loads, NO wait (caller drains once for all in-flight loads)
__device__ __forceinline__ void ld4_nw(float4& a, float4& b, float4& c, float4& d,
                                       const float4* p0, const float4* p1,
                                       const float4* p2, const float4* p3)
{
    asm volatile(
        "global_load_dwordx4 %0, %4, off sc0 sc1\n\t"
        "global_load_dwordx4 %1, %5, off sc0 sc1\n\t"
        "global_load_dwordx4 %2, %6, off sc0 sc1\n\t"
        "global_load_dwordx4 %3, %7, off sc0 sc1"
        : "=&v"(a), "=&v"(b), "=&v"(c), "=&v"(d)
        : "v"(p0), "v"(p1), "v"(p2), "v"(p3)
        : "memory");
}

__device__ __forceinline__ void arrive_wait(unsigned* bar, int g, unsigned tgt)
{
    unsigned r = __hip_atomic_fetch_add(bar + g * 32, 1u, __ATOMIC_RELAXED,
                                        __HIP_MEMORY_SCOPE_AGENT);
    if (r == tgt * GRPSZ - 1) {
        unsigned rr = __hip_atomic_fetch_add(bar + 256, 1u, __ATOMIC_RELAXED,
                                             __HIP_MEMORY_SCOPE_AGENT);
        if (rr == tgt * NGRP - 1)
            __hip_atomic_store(bar + 288, tgt, __ATOMIC_RELAXED,
                               __HIP_MEMORY_SCOPE_AGENT);
    }
    int spins = 0;
    while (__hip_atomic_load(bar + 288, __ATOMIC_RELAXED,
                             __HIP_MEMORY_SCOPE_AGENT) < tgt) {
        __builtin_amdgcn_s_sleep(2);
        if (++spins > 30000) break;
    }
}

__device__ __forceinline__ float dot32(const float* hb, const float (&w)[32])
{
    float a0 = 0.f, a1 = 0.f, a2 = 0.f, a3 = 0.f;
    #pragma unroll
    for (int k4 = 0; k4 < 8; k4++) {
        float4 h4 = ((const float4*)hb)[k4];
        a0 = fmaf(h4.x, w[k4 * 4 + 0], a0);
        a1 = fmaf(h4.y, w[k4 * 4 + 1], a1);
        a2 = fmaf(h4.z, w[k4 * 4 + 2], a2);
        a3 = fmaf(h4.w, w[k4 * 4 + 3], a3);
    }
    return (a0 + a1) + (a2 + a3);
}

// 256 blocks; block owns h1 units {2bid,2bid+1} AND h2 units {2bid,2bid+1}.
// Iteration s computes h1[s] (s<512) and h2[s-1] (s>=1).
// Dot mapping (R4-proven, conflict-free): cl = t&15 (column), ks = t>>4
// (K-slice; only 4 distinct per wave -> 16-lane broadcast LDS reads).
// Columns 0..7 = L1 gates (gate=cl>>1, unit=cl&1); 8..15 = L2 gates.
// UNIFORM dot phase: every thread does dot(hl1,w1)+dot(hl2,w2); L1 threads
// have w2=0 (their hl2 dot adds 0) -> zero divergence, zero conflicts.
__global__ __launch_bounds__(256)
void lstm_fused_kernel(const float* __restrict__ P1,
                       const float* __restrict__ wh1,
                       const float* __restrict__ wi2,
                       const float* __restrict__ wh2,
                       const float* __restrict__ bi2,
                       const float* __restrict__ bh2,
                       float* __restrict__ H2out,
                       float* __restrict__ h1A, float* __restrict__ h1B,
                       float* __restrict__ h2A, float* __restrict__ h2B,
                       unsigned* __restrict__ bar)
{
    __shared__ float hl1[16 * 512];        // 32 KB: h1[s-1]
    __shared__ float hl2[16 * 512];        // 32 KB: h2[s-2]
    __shared__ float part[16 * 257];       // [ks][cl*16+b], padded
    __shared__ float gl[256];              // 16 cols x 16 batch
    __shared__ float c_l1[32], c_l2[32];   // cell states (2 units x 16 batch)

    const int t = threadIdx.x, bid = blockIdx.x;
    const int g = bid >> 5;
    const int cl = t & 15, ks = t >> 4;    // dot-phase mapping (R4-proven)
    const int cc = cl & 7, gate_d = cc >> 1, jj_d = cc & 1;
    const int rc = t >> 4, rb = t & 15;    // reduce-phase mapping
    const int rcc = rc & 7, gate_r = rcc >> 1, jj_r = rcc & 1;
    const int j2 = 2 * bid;

    float w1[32];   // cl<8: wh1 row | cl>=8: wi2 row
    float w2[32];   // cl<8: zeros   | cl>=8: wh2 row
    {
        const float* wrow = ((cl < 8) ? wh1 : wi2)
                          + (size_t)(gate_d * 512 + j2 + jj_d) * 512 + ks * 32;
        #pragma unroll
        for (int i = 0; i < 32; i++) w1[i] = wrow[i];
    }
    if (cl >= 8) {
        const float* wrow = wh2 + (size_t)(gate_d * 512 + j2 + jj_d) * 512 + ks * 32;
        #pragma unroll
        for (int i = 0; i < 32; i++) w2[i] = wrow[i];
    } else {
        #pragma unroll
        for (int i = 0; i < 32; i++) w2[i] = 0.f;
    }
    float bias2v = 0.f;
    if (rc >= 8) {
        int col = gate_r * 512 + j2 + jj_r;
        bias2v = bi2[col] + bh2[col];
    }
    // init: zero cell states; zero h1[-1] (h1B), h2[-1] (h2B)
    if (t < 32) {
        c_l1[t] = 0.f; c_l2[t] = 0.f;
        int b = t >> 1, jj = t & 1;
        __hip_atomic_store(&h1B[b * 512 + j2 + jj], 0.f,
                           __ATOMIC_RELAXED, __HIP_MEMORY_SCOPE_AGENT);
        __hip_atomic_store(&h2B[b * 512 + j2 + jj], 0.f,
                           __ATOMIC_RELAXED, __HIP_MEMORY_SCOPE_AGENT);
    }
    wait_vm0();
    __syncthreads();
    if (t == 0) arrive_wait(bar, g, 1);
    __syncthreads();

    for (int s = 0; s <= 512; s++) {
        // ---- stage h1[s-1] and h2[s-2]: 16 coherent loads, ONE drain ----
        {
            const float* h1src = (s & 1) ? h1A : h1B;   // buffer (s-1)&1
            const float* h2src = (s & 1) ? h2B : h2A;   // buffer (s-2)&1
            const float4* a4 = (const float4*)h1src;
            const float4* b4 = (const float4*)h2src;
            float4 r0,r1,r2,r3,r4,r5,r6,r7,r8,r9,r10,r11,r12,r13,r14,r15;
            ld4_nw(r0, r1, r2, r3,   a4 + t,        a4 + t + 256,  a4 + t + 512,  a4 + t + 768);
            ld4_nw(r4, r5, r6, r7,   a4 + t + 1024, a4 + t + 1280, a4 + t + 1536, a4 + t + 1792);
            ld4_nw(r8, r9, r10,r11,  b4 + t,        b4 + t + 256,  b4 + t + 512,  b4 + t + 768);
            ld4_nw(r12,r13,r14,r15,  b4 + t + 1024, b4 + t + 1280, b4 + t + 1536, b4 + t + 1792);
            wait_vm0();
            float4* d1 = (float4*)hl1; float4* d2 = (float4*)hl2;
            d1[t] = r0;        d1[t + 256] = r1;  d1[t + 512] = r2;  d1[t + 768] = r3;
            d1[t + 1024] = r4; d1[t + 1280] = r5; d1[t + 1536] = r6; d1[t + 1792] = r7;
            d2[t] = r8;        d2[t + 256] = r9;  d2[t + 512] = r10; d2[t + 768] = r11;
            d2[t + 1024] = r12; d2[t + 1280] = r13; d2[t + 1536] = r14; d2[t + 1792] = r15;
        }
        // prefetch P1 gate value (cached load, in flight during dot phase)
        float pv = 0.f;
        if (rc < 8 && s < 512)
            pv = P1[(size_t)(rb * 512 + s) * 2048 + gate_r * 512 + j2 + jj_r];
        __syncthreads();

        // ---- uniform dot phase: no branches, broadcast LDS reads ----
        float accb[16];
        #pragma unroll
        for (int b = 0; b < 16; b++)
            accb[b] = dot32(hl1 + b * 512 + ks * 32, w1)
                    + dot32(hl2 + b * 512 + ks * 32, w2);
        #pragma unroll
        for (int b = 0; b < 16; b++)
            part[ks * 257 + cl * 16 + b] = accb[b];
        __syncthreads();

        // ---- reduce + bias ----
        {
            float gv = (rc < 8) ? pv : bias2v;
            #pragma unroll
            for (int k = 0; k < 16; k++)
                gv += part[k * 257 + rc * 16 + rb];
            gl[rc * 16 + rb] = gv;
        }
        __syncthreads();

        // ---- cell update + coherent h store ----
        if (t < 64) {
            if (t < 32) {
                if (s < 512) {
                    int jj = t >> 4, b = t & 15;
                    float iv = gl[(0 + jj) * 16 + b];
                    float fv = gl[(2 + jj) * 16 + b];
                    float gg = gl[(4 + jj) * 16 + b];
                    float ov = gl[(6 + jj) * 16 + b];
                    float ig = 1.f / (1.f + expf(-iv));
                    float fg = 1.f / (1.f + expf(-fv));
                    float og = 1.f / (1.f + expf(-ov));
                    float cn = fg * c_l1[jj * 16 + b] + ig * tanhf(gg);
                    float hn = og * tanhf(cn);
                    c_l1[jj * 16 + b] = cn;
                    float* hout = (s & 1) ? h1B : h1A;       // buffer s&1
                    __hip_atomic_store(&hout[b * 512 + j2 + jj], hn,
                                       __ATOMIC_RELAXED, __HIP_MEMORY_SCOPE_AGENT);
                }
            } else {
                if (s >= 1) {
                    int tt = t - 32;
                    int jj = tt >> 4, b = tt & 15;
                    int m = s - 1;
                    float iv = gl[(8 + jj) * 16 + b];
                    float fv = gl[(10 + jj) * 16 + b];
                    float gg = gl[(12 + jj) * 16 + b];
                    float ov = gl[(14 + jj) * 16 + b];
                    float ig = 1.f / (1.f + expf(-iv));
                    float fg = 1.f / (1.f + expf(-fv));
                    float og = 1.f / (1.f + expf(-ov));
                    float cn = fg * c_l2[jj * 16 + b] + ig * tanhf(gg);
                    float hn = og * tanhf(cn);
                    c_l2[jj * 16 + b] = cn;
                    float* hout = (s & 1) ? h2A : h2B;       // buffer (s-1)&1
                    __hip_atomic_store(&hout[b * 512 + j2 + jj], hn,
                                       __ATOMIC_RELAXED, __HIP_MEMORY_SCOPE_AGENT);
                    H2out[(size_t)(b * 512 + m) * 512 + j2 + jj] = hn;
                }
            }
        }
        if (s < 512) {
            wait_vm0();                       // drain write-through h stores
            if (t == 0) arrive_wait(bar, g, (unsigned)(s + 2));
            __syncthreads();
        }
    }
}

__global__ void finalize_loss_kernel(const float* __restrict__ acc, float* __restrict__ out)
{
    int q = threadIdx.x;
    if (q < 4) out[2621440 + q] = acc[q] * (1.f / 4194304.f);
}

extern "C" void kernel_launch(void* const* d_in, const int* in_sizes, int n_in,
                              void* d_out, int out_size, void* d_ws, size_t ws_size,
                              hipStream_t stream)
{
    const float* waveform  = (const float*)d_in[0];
    const float* enc_w     = (const float*)d_in[1];
    const float* enc_b     = (const float*)d_in[2];
    const float* ln_g      = (const float*)d_in[3];
    const float* ln_b      = (const float*)d_in[4];
    const float* codebooks = (const float*)d_in[5];
    const float* lstm_wi   = (const float*)d_in[6];
    const float* lstm_wh   = (const float*)d_in[7];
    const float* lstm_bi   = (const float*)d_in[8];
    const float* lstm_bh   = (const float*)d_in[9];
    const float* dec_w     = (const float*)d_in[10];
    const float* dec_b     = (const float*)d_in[11];
    float* out = (float*)d_out;

    float* ws = (float*)d_ws;                  // float offsets
    float* residual = ws;                      // 4,194,304
    float* quant    = ws + 4194304;            // 4,194,304
    float* H2       = ws + 8388608;            // 4,194,304
    float* big      = ws + 12582912;           // 16,777,216 (VQ D, then LSTM P1)
    float* h1A      = ws + 29360128;           // 8192
    float* h1B      = ws + 29368320;           // 8192
    float* h2A      = ws + 29376512;           // 8192
    float* h2B      = ws + 29384704;           // 8192
    float* norms    = ws + 29392896;           // 4096
    float* loss_acc = ws + 29396992;           // 16
    unsigned* bar   = (unsigned*)(ws + 29397504); // 512 u32

    hipMemsetAsync(loss_acc, 0, 16 * sizeof(float), stream);
    hipMemsetAsync(bar, 0, 512 * sizeof(unsigned), stream);

    // Encoder
    gemm64<false><<<dim3(8, 128), 256, 0, stream>>>(waveform, enc_w, residual,
                                                    8192, 512, 320, enc_b, nullptr);
    ln_relu_kernel<<<8192, 256, 0, stream>>>(residual, ln_g, ln_b);

    // Residual VQ
    rownorm_kernel<<<4096, 256, 0, stream>>>(codebooks, norms);
    for (int q = 0; q < 4; q++) {
        const float* cb = codebooks + (size_t)q * 1024 * 512;
        gemm64<true><<<dim3(16, 128), 256, 0, stream>>>(residual, cb, big,
                                                        8192, 1024, 512, nullptr, nullptr);
        vq_update_kernel<<<8192, 256, 0, stream>>>(big, norms + q * 1024, cb,
                                                   residual, quant, loss_acc + q, q == 0);
    }

    // P1 = quant @ wi1^T + bi1 + bh1
    gemm64<true><<<dim3(32, 128), 256, 0, stream>>>(quant, lstm_wi, big,
                                                    8192, 2048, 512, lstm_bi, lstm_bh);
    // Fused 2-layer LSTM — merged roles, uniform dot, single-drain staging
    lstm_fused_kernel<<<dim3(256), dim3(256), 0, stream>>>(
        big, lstm_wh, lstm_wi + (size_t)2048 * 512, lstm_wh + (size_t)2048 * 512,
        lstm_bi + 2048, lstm_bh + 2048, H2, h1A, h1B, h2A, h2B, bar);

    // Decoder -> d_out
    gemm64<false><<<dim3(5, 128), 256, 0, stream>>>(H2, dec_w, out,
                                                    8192, 320, 512, dec_b, nullptr);
    finalize_loss_kernel<<<1, 4, 0, stream>>>(loss_acc, out);
}